// Round 10
// baseline (503.054 us; speedup 1.0000x reference)
//
#include <hip/hip_runtime.h>
#include <hip/hip_bf16.h>

#define D 128
#define MAXB 512

typedef __attribute__((ext_vector_type(8))) short short8;
typedef __attribute__((ext_vector_type(4))) float float4v;
typedef __attribute__((ext_vector_type(2))) float float2v;

__device__ __forceinline__ float4v mfma16(short8 a, short8 b, float4v c) {
  return __builtin_amdgcn_mfma_f32_16x16x32_bf16(a, b, c, 0, 0, 0);
}
__device__ __forceinline__ float b2f(__hip_bfloat16 x) { return __bfloat162float(x); }
__device__ __forceinline__ __hip_bfloat16 f2b(float x) { return __float2bfloat16(x); }
__device__ __forceinline__ unsigned short f2b_bits(float x) {
  __hip_bfloat16 h = __float2bfloat16(x);
  return *reinterpret_cast<unsigned short*>(&h);
}

__device__ __forceinline__ float ldf(const float* p, size_t i) { return p[i]; }
__device__ __forceinline__ float ldf(const __hip_bfloat16* p, size_t i) { return b2f(p[i]); }
__device__ __forceinline__ void stf(float* p, size_t i, float v) { p[i] = v; }
__device__ __forceinline__ void stf(__hip_bfloat16* p, size_t i, float v) { p[i] = f2b(v); }

// relaxed workgroup barrier: drain LDS ops only, leave global loads in flight.
__device__ __forceinline__ void bar_lds() {
  asm volatile("s_waitcnt lgkmcnt(0)\n\ts_barrier" ::: "memory");
}

// packed bf16-pair -> float2 (lo, hi)
__device__ __forceinline__ float2v up2(unsigned w) {
  float2v r;
  r.x = __uint_as_float(w << 16);
  r.y = __uint_as_float(w & 0xffff0000u);
  return r;
}
// fp8 e4m3 (OCP on gfx950) encode/decode via the HW cvt pair — self-consistent.
__device__ __forceinline__ unsigned char f2fp8(float x) {
  int r = __builtin_amdgcn_cvt_pk_fp8_f32(x, x, 0, false);
  return (unsigned char)(r & 0xff);
}
__device__ __forceinline__ float2v cvt2lo(unsigned w) {
  return __builtin_amdgcn_cvt_pk_f32_fp8(w, false);
}
__device__ __forceinline__ float2v cvt2hi(unsigned w) {
  return __builtin_amdgcn_cvt_pk_f32_fp8(w, true);
}

__device__ __forceinline__ short8 cvt8(float4 u0, float4 u1) {
  short8 a;
  a[0] = (short)f2b_bits(u0.x); a[1] = (short)f2b_bits(u0.y);
  a[2] = (short)f2b_bits(u0.z); a[3] = (short)f2b_bits(u0.w);
  a[4] = (short)f2b_bits(u1.x); a[5] = (short)f2b_bits(u1.y);
  a[6] = (short)f2b_bits(u1.z); a[7] = (short)f2b_bits(u1.w);
  return a;
}

// ------- bucket histogram (LDS-combined) + weight cast folded in (independent) ----
// frag layout for weights (KxNcol): out[((c*4+quad)*Ncol + col)*8 + j]
//   = W[(c*32 + quad*8 + j)*Ncol + col]  -> one aligned 16-B load per fragment.
__global__ __launch_bounds__(256) void k_bhist_cast(
    const int* __restrict__ dst, int* __restrict__ bh, int E,
    const float* __restrict__ wq, const float* __restrict__ wk,
    const float* __restrict__ wv, const float* __restrict__ wo,
    const float* __restrict__ w1, const float* __restrict__ w2,
    __hip_bfloat16* __restrict__ oq, __hip_bfloat16* __restrict__ ok,
    __hip_bfloat16* __restrict__ ov, __hip_bfloat16* __restrict__ oo,
    __hip_bfloat16* __restrict__ o1, __hip_bfloat16* __restrict__ o2) {
  __shared__ int cnt[MAXB];
  const int t = threadIdx.x;
  const int gid = blockIdx.x * 256 + t;
  for (int i = t; i < MAXB; i += 256) cnt[i] = 0;
  __syncthreads();
  for (int e = gid; e < E; e += gridDim.x * 256) atomicAdd(&cnt[dst[e] >> 8], 1);
  // weight cast: 131072 elements, done by the first 131072 threads
  int i = gid;
  if (i < 65536) {  // wq, wk, wv, wo : K=128, Ncol=128
    int m = i & 16383;
    int which = i >> 14;
    const float* s = (which == 0) ? wq : (which == 1) ? wk : (which == 2) ? wv : wo;
    __hip_bfloat16* o = (which == 0) ? oq : (which == 1) ? ok : (which == 2) ? ov : oo;
    int j = m & 7, t2 = m >> 3;
    int col = t2 & 127, cq = t2 >> 7;
    o[m] = f2b(s[((cq >> 2) * 32 + (cq & 3) * 8 + j) * 128 + col]);
  } else if (i < 98304) {  // w1 : K=128, Ncol=256
    int m = i - 65536;
    int j = m & 7, t2 = m >> 3;
    int col = t2 & 255, cq = t2 >> 8;
    o1[m] = f2b(w1[((cq >> 2) * 32 + (cq & 3) * 8 + j) * 256 + col]);
  } else if (i < 131072) {  // w2 : K=256, Ncol=128
    int m = i - 98304;
    int j = m & 7, t2 = m >> 3;
    int col = t2 & 127, cq = t2 >> 7;
    o2[m] = f2b(w2[((cq >> 2) * 32 + (cq & 3) * 8 + j) * 128 + col]);
  }
  __syncthreads();
  for (int k = t; k < MAXB; k += 256)
    if (cnt[k]) atomicAdd(&bh[k], cnt[k]);
}

__global__ void k_bscan(const int* __restrict__ bh, int* __restrict__ bbase,
                        int* __restrict__ bcur, int B) {
  __shared__ int sd[MAXB];
  int t = threadIdx.x;
  int v = (t < B) ? bh[t] : 0;
  sd[t] = v;
  __syncthreads();
  for (int o = 1; o < MAXB; o <<= 1) {
    int x = (t >= o) ? sd[t - o] : 0;
    __syncthreads();
    sd[t] += x;
    __syncthreads();
  }
  if (t < B) {
    int e = sd[t] - v;
    bbase[t] = e;
    bcur[t] = e;
  }
}

// each block bins 4096 edges into contiguous per-bucket runs (packed 32-bit)
__global__ __launch_bounds__(256) void k_bin(const int* __restrict__ src,
                                             const int* __restrict__ dst,
                                             int* __restrict__ bcur,
                                             unsigned* __restrict__ binned, int E) {
  __shared__ int cnt[MAXB];
  __shared__ int base[MAXB];
  const int t = threadIdx.x;
  const int e0 = blockIdx.x * 4096;
  for (int i = t; i < MAXB; i += 256) cnt[i] = 0;
  __syncthreads();
  int myb[16], myr[16];
  unsigned pk[16];
#pragma unroll
  for (int j = 0; j < 16; ++j) {
    int e = e0 + j * 256 + t;
    if (e < E) {
      int d = dst[e];
      pk[j] = ((unsigned)src[e] << 8) | (unsigned)(d & 255);
      int b = d >> 8;
      myb[j] = b;
      myr[j] = atomicAdd(&cnt[b], 1);
    } else {
      myb[j] = -1;
    }
  }
  __syncthreads();
  for (int i = t; i < MAXB; i += 256)
    base[i] = cnt[i] ? atomicAdd(&bcur[i], cnt[i]) : 0;
  __syncthreads();
#pragma unroll
  for (int j = 0; j < 16; ++j)
    if (myb[j] >= 0) binned[(size_t)base[myb[j]] + myr[j]] = pk[j];
}

// one block per bucket: per-node deg/offs + LDS-local fine scatter into csr
__global__ __launch_bounds__(256) void k_fine(const unsigned* __restrict__ binned,
                                              const int* __restrict__ bh,
                                              const int* __restrict__ bbase,
                                              int* __restrict__ deg,
                                              int* __restrict__ offs,
                                              int* __restrict__ csr, int N) {
  __shared__ int cnt[256];
  __shared__ int cur[256];
  __shared__ int sd[256];
  const int b = blockIdx.x, t = threadIdx.x;
  const int node0 = b << 8;
  cnt[t] = 0;
  __syncthreads();
  const int s0 = bbase[b], len = bh[b];
  for (int i = t; i < len; i += 256) atomicAdd(&cnt[binned[(size_t)s0 + i] & 255], 1);
  __syncthreads();
  int v = cnt[t];
  sd[t] = v;
  __syncthreads();
  for (int o = 1; o < 256; o <<= 1) {
    int x = (t >= o) ? sd[t - o] : 0;
    __syncthreads();
    sd[t] += x;
    __syncthreads();
  }
  int excl = sd[t] - v;
  cur[t] = excl;
  int node = node0 + t;
  if (node < N) {
    deg[node] = v;
    offs[node] = s0 + excl;
  }
  __syncthreads();
  for (int i = t; i < len; i += 256) {
    unsigned ed = binned[(size_t)s0 + i];
    int p = atomicAdd(&cur[ed & 255], 1);
    csr[s0 + p] = (int)(ed >> 8);
  }
}

// ------- fused QKV GEMM v7: one WAVE per 16-row tile, all 8 col-tiles x Q,K,V -----
// 96 MFMA per wave-iteration; weights in LDS (96 KB); no barriers in the loop.
__global__ __launch_bounds__(512) void gemm_qkv7(const float* __restrict__ A,
                                                 const uint4* __restrict__ wqF,
                                                 const uint4* __restrict__ wkF,
                                                 const uint4* __restrict__ wvF,
                                                 __hip_bfloat16* __restrict__ Q,
                                                 unsigned char* __restrict__ KV8,
                                                 int Nrow) {
  __shared__ short W[3 * 16384];  // 96 KB: Wq | Wk | Wv, frag-ordered
  const int t = threadIdx.x;
  {
    uint4* W4 = (uint4*)W;
    for (int i = t; i < 2048; i += 512) {
      W4[i] = wqF[i];
      W4[i + 2048] = wkF[i];
      W4[i + 4096] = wvF[i];
    }
  }
  __syncthreads();
  const int w = t >> 6;            // wave 0..7 — independent tile stream
  const int lane = t & 63;
  const int n = lane & 15, quad = lane >> 4;
  const int ntiles = Nrow >> 4;
  const int step = gridDim.x * 8;
  int rt = blockIdx.x * 8 + w;
  if (rt >= ntiles) return;
  float4 u[8];
  {
    const float* Ap = A + (size_t)(rt * 16 + n) * 128 + quad * 8;
#pragma unroll
    for (int c = 0; c < 4; ++c) {
      u[2 * c] = *(const float4*)(Ap + c * 32);
      u[2 * c + 1] = *(const float4*)(Ap + c * 32 + 4);
    }
  }
  while (true) {
    const int rtn = rt + step;
    const bool more = rtn < ntiles;
    float4 un[8];
    if (more) {  // 1-deep prefetch
      const float* Ap = A + (size_t)(rtn * 16 + n) * 128 + quad * 8;
#pragma unroll
      for (int c = 0; c < 4; ++c) {
        un[2 * c] = *(const float4*)(Ap + c * 32);
        un[2 * c + 1] = *(const float4*)(Ap + c * 32 + 4);
      }
    }
    short8 a[4];
#pragma unroll
    for (int c = 0; c < 4; ++c) a[c] = cvt8(u[2 * c], u[2 * c + 1]);
    float4v aq[8], ak[8], av[8];
#pragma unroll
    for (int ct2 = 0; ct2 < 8; ++ct2) {
      aq[ct2] = (float4v){0.f, 0.f, 0.f, 0.f};
      ak[ct2] = aq[ct2];
      av[ct2] = aq[ct2];
    }
#pragma unroll
    for (int c = 0; c < 4; ++c) {
      const short8 af = a[c];
      const int fb = ((c * 4 + quad) * 128 + n) * 8;
#pragma unroll
      for (int ct2 = 0; ct2 < 8; ++ct2) {
        const int fo = fb + ct2 * 128;  // +ct2*16 cols, *8 shorts
        aq[ct2] = mfma16(af, *(const short8*)&W[fo], aq[ct2]);
        ak[ct2] = mfma16(af, *(const short8*)&W[16384 + fo], ak[ct2]);
        av[ct2] = mfma16(af, *(const short8*)&W[32768 + fo], av[ct2]);
      }
    }
#pragma unroll
    for (int r = 0; r < 4; ++r) {
      const int grow = rt * 16 + quad * 4 + r;
      const size_t qb = (size_t)grow * 128 + n;
      const size_t kb = (size_t)grow * 256 + ((n >> 3) << 4) + (n & 7);
#pragma unroll
      for (int ct2 = 0; ct2 < 8; ++ct2) {
        Q[qb + ct2 * 16] = f2b(aq[ct2][r]);
        KV8[kb + ct2 * 32] = f2fp8(ak[ct2][r]);
        KV8[kb + ct2 * 32 + 8] = f2fp8(av[ct2][r]);
      }
    }
    if (!more) break;
#pragma unroll
    for (int i = 0; i < 8; ++i) u[i] = un[i];
    rt = rtn;
  }
}

// ------ GEMM + bias + residual + LayerNorm v2: one WAVE per 16-row tile ----------
// 32 MFMA per wave-iter; LN fully in-wave (shfl over n-lanes); zero loop barriers.
__global__ __launch_bounds__(512) void ln_gemm2(const short* __restrict__ A,
                                                const uint4* __restrict__ BF4,
                                                const float* __restrict__ bias,
                                                const float* __restrict__ resid,
                                                const float* __restrict__ gam,
                                                const float* __restrict__ bet,
                                                __hip_bfloat16* __restrict__ Out,
                                                int Nrow) {
  __shared__ short W[16384];  // 32 KB, frag-ordered (K=128 x 128 cols)
  const int t = threadIdx.x;
  {
    uint4* W4 = (uint4*)W;
    for (int i = t; i < 2048; i += 512) W4[i] = BF4[i];
  }
  __syncthreads();
  const int w = t >> 6;
  const int lane = t & 63;
  const int n = lane & 15, quad = lane >> 4;
  float gv[8], bv[8], biasv[8];
#pragma unroll
  for (int ct2 = 0; ct2 < 8; ++ct2) {
    gv[ct2] = gam[ct2 * 16 + n];
    bv[ct2] = bet[ct2 * 16 + n];
    biasv[ct2] = bias[ct2 * 16 + n];
  }
  const int ntiles = Nrow >> 4;
  for (int rt = blockIdx.x * 8 + w; rt < ntiles; rt += gridDim.x * 8) {
    const short8* Ap = (const short8*)(A + (size_t)(rt * 16 + n) * 128 + quad * 8);
    short8 a[4];
#pragma unroll
    for (int c = 0; c < 4; ++c) a[c] = Ap[c * 4];
    float4v acc[8];
#pragma unroll
    for (int ct2 = 0; ct2 < 8; ++ct2) acc[ct2] = (float4v){0.f, 0.f, 0.f, 0.f};
#pragma unroll
    for (int c = 0; c < 4; ++c) {
      const short8 af = a[c];
      const int fb = ((c * 4 + quad) * 128 + n) * 8;
#pragma unroll
      for (int ct2 = 0; ct2 < 8; ++ct2)
        acc[ct2] = mfma16(af, *(const short8*)&W[fb + ct2 * 128], acc[ct2]);
    }
    // bias + residual
#pragma unroll
    for (int r = 0; r < 4; ++r) {
      const size_t base = (size_t)(rt * 16 + quad * 4 + r) * 128 + n;
#pragma unroll
      for (int ct2 = 0; ct2 < 8; ++ct2)
        acc[ct2][r] += biasv[ct2] + resid[base + ct2 * 16];
    }
    // in-wave LayerNorm: rows (quad*4+r) live on the 16 n-lanes of this quad group
    float s[4] = {0.f, 0.f, 0.f, 0.f}, s2[4] = {0.f, 0.f, 0.f, 0.f};
#pragma unroll
    for (int ct2 = 0; ct2 < 8; ++ct2)
#pragma unroll
      for (int r = 0; r < 4; ++r) {
        float x = acc[ct2][r];
        s[r] += x;
        s2[r] += x * x;
      }
#pragma unroll
    for (int r = 0; r < 4; ++r)
#pragma unroll
      for (int o = 1; o <= 8; o <<= 1) {
        s[r] += __shfl_xor(s[r], o);
        s2[r] += __shfl_xor(s2[r], o);
      }
#pragma unroll
    for (int r = 0; r < 4; ++r) {
      float mean = s[r] * 0.0078125f;
      float var = s2[r] * 0.0078125f - mean * mean;
      float rstd = rsqrtf(var + 1e-5f);
      const size_t base = (size_t)(rt * 16 + quad * 4 + r) * 128 + n;
#pragma unroll
      for (int ct2 = 0; ct2 < 8; ++ct2)
        Out[base + ct2 * 16] = f2b((acc[ct2][r] - mean) * rstd * gv[ct2] + bv[ct2]);
    }
  }
}

// ------ fused FFN: W1+W2 in LDS (128 KB), ping-pong mid, 2 barriers/iter ----------
__global__ __launch_bounds__(512) void ffn_ln(const short* __restrict__ hh,
                                              const uint4* __restrict__ W1F4,
                                              const float* __restrict__ c1,
                                              const uint4* __restrict__ W2F4,
                                              const float* __restrict__ c2,
                                              const float* __restrict__ gam,
                                              const float* __restrict__ bet,
                                              float* __restrict__ Out, int Nrow) {
  __shared__ short W1[32768];         // 64 KB frag-ordered
  __shared__ short W2[32768];         // 64 KB frag-ordered
  __shared__ short mid[2][16][264];   // ping-pong
  __shared__ float tile[16][132];
  const int t = threadIdx.x;
  {
    uint4* a4 = (uint4*)W1;
    uint4* b4 = (uint4*)W2;
    for (int i = t; i < 4096; i += 512) {
      a4[i] = W1F4[i];
      b4[i] = W2F4[i];
    }
  }
  __syncthreads();
  const int lane = t & 63;
  const int wv = t >> 6;
  const int n = lane & 15, quad = lane >> 4;
  float b1v0 = c1[(wv * 2) * 16 + n], b1v1 = c1[(wv * 2 + 1) * 16 + n];
  float b2v = c2[wv * 16 + n];
  const int row2 = t >> 5, sub = t & 31;
  float ga0 = gam[sub],      ga1 = gam[sub + 32];
  float ga2 = gam[sub + 64], ga3 = gam[sub + 96];
  float be0 = bet[sub],      be1 = bet[sub + 32];
  float be2 = bet[sub + 64], be3 = bet[sub + 96];
  const int ntiles = Nrow >> 4;
  const __hip_bfloat16* hb = (const __hip_bfloat16*)hh;
  const int f1b0 = quad * 256 + (wv * 2) * 16 + n;
  const int f1b1 = quad * 256 + (wv * 2 + 1) * 16 + n;
  const int f2b = quad * 128 + wv * 16 + n;
  int rt = blockIdx.x;
  if (rt >= ntiles) return;
  short8 a[4];
  __hip_bfloat16 rs[4];
  {
    const short8* Ap = (const short8*)(hh + (size_t)(rt * 16 + n) * 128 + quad * 8);
#pragma unroll
    for (int c = 0; c < 4; ++c) a[c] = Ap[c * 4];
#pragma unroll
    for (int r = 0; r < 4; ++r)
      rs[r] = hb[(size_t)(rt * 16 + quad * 4 + r) * 128 + wv * 16 + n];
  }
  int mp = 0;
  while (true) {
    const int rtn = rt + gridDim.x;
    const bool more = rtn < ntiles;
    short8 an[4];
    __hip_bfloat16 rsn[4];
    if (more) {  // prefetch survives the relaxed barriers (lgkm-only drain)
      const short8* Ap = (const short8*)(hh + (size_t)(rtn * 16 + n) * 128 + quad * 8);
#pragma unroll
      for (int c = 0; c < 4; ++c) an[c] = Ap[c * 4];
#pragma unroll
      for (int r = 0; r < 4; ++r)
        rsn[r] = hb[(size_t)(rtn * 16 + quad * 4 + r) * 128 + wv * 16 + n];
    }
    // GEMM1: mid = relu(hh @ W1 + c1)
    float4v a10 = {0.f, 0.f, 0.f, 0.f}, a11 = a10;
#pragma unroll
    for (int c = 0; c < 4; ++c) {
      short8 f1a = *(const short8*)&W1[(f1b0 + c * 1024) * 8];
      short8 f1c = *(const short8*)&W1[(f1b1 + c * 1024) * 8];
      a10 = mfma16(a[c], f1a, a10);
      a11 = mfma16(a[c], f1c, a11);
    }
#pragma unroll
    for (int r = 0; r < 4; ++r) {
      mid[mp][quad * 4 + r][(wv * 2) * 16 + n] = (short)f2b_bits(fmaxf(a10[r] + b1v0, 0.f));
      mid[mp][quad * 4 + r][(wv * 2 + 1) * 16 + n] = (short)f2b_bits(fmaxf(a11[r] + b1v1, 0.f));
    }
    bar_lds();
    // GEMM2: acc = mid @ W2 over K=256
    float4v acc = {0.f, 0.f, 0.f, 0.f};
#pragma unroll
    for (int c = 0; c < 8; ++c) {
      short8 am = *(const short8*)&mid[mp][n][quad * 8 + c * 32];
      short8 f2 = *(const short8*)&W2[(f2b + c * 512) * 8];
      acc = mfma16(am, f2, acc);
    }
#pragma unroll
    for (int r = 0; r < 4; ++r)
      tile[quad * 4 + r][wv * 16 + n] = acc[r] + b2v + b2f(rs[r]);
    bar_lds();
    float x0 = tile[row2][sub], x1 = tile[row2][sub + 32];
    float x2 = tile[row2][sub + 64], x3 = tile[row2][sub + 96];
    float s = x0 + x1 + x2 + x3;
    float s2 = x0 * x0 + x1 * x1 + x2 * x2 + x3 * x3;
#pragma unroll
    for (int o = 16; o >= 1; o >>= 1) {
      s += __shfl_xor(s, o);
      s2 += __shfl_xor(s2, o);
    }
    float mean = s * 0.0078125f;
    float var = s2 * 0.0078125f - mean * mean;
    float rstd = rsqrtf(var + 1e-5f);
    size_t base = (size_t)(rt * 16 + row2) * 128;
    Out[base + sub]      = (x0 - mean) * rstd * ga0 + be0;
    Out[base + sub + 32] = (x1 - mean) * rstd * ga1 + be1;
    Out[base + sub + 64] = (x2 - mean) * rstd * ga2 + be2;
    Out[base + sub + 96] = (x3 - mean) * rstd * ga3 + be3;
    if (!more) break;
#pragma unroll
    for (int c = 0; c < 4; ++c) a[c] = an[c];
#pragma unroll
    for (int r = 0; r < 4; ++r) rs[r] = rsn[r];
    rt = rtn;
    mp ^= 1;
  }
}

// ---- attention aggregation v5: fp8 KV gather (256 B/edge), lane = (e4, hd, hf) ----
__global__ __launch_bounds__(256) void attn_agg5(const uint4* __restrict__ Q4,
                                                 const uint4* __restrict__ KV8,
                                                 const int* __restrict__ offs,
                                                 const int* __restrict__ deg,
                                                 const int* __restrict__ csr,
                                                 uint4* __restrict__ AT4, int N) {
  const int lane = threadIdx.x & 63;
  const int wv = threadIdx.x >> 6;
  const int e4 = lane >> 4;        // 0..3  edge slot
  const int hd = (lane >> 1) & 7;  // head
  const int hf = lane & 1;         // half-head: dims hf*8 .. hf*8+7
  const int kvo = hd * 2 + hf;     // uint4 index within a node's 16 x 16B
  for (int node = blockIdx.x * 4 + wv; node < N; node += gridDim.x * 4) {
    uint4 qa = Q4[(size_t)node * 16 + kvo];
    float2v qv[4];
    qv[0] = up2(qa.x); qv[1] = up2(qa.y); qv[2] = up2(qa.z); qv[3] = up2(qa.w);
    float2v acc[4];
#pragma unroll
    for (int d = 0; d < 4; ++d) acc[d] = (float2v){0.f, 0.f};
    float z = 0.f;
    const int st = offs[node], dg = deg[node];
    if (dg > 0) {
      const int dgm1 = dg - 1;
      int s_cur = csr[st + min(e4, dgm1)];
      int s_nxt = (dg > 4) ? csr[st + min(4 + e4, dgm1)] : s_cur;
      uint4 ckv = KV8[(size_t)s_cur * 16 + kvo];
      int i = 0;
      while (true) {
        const bool more = (i + 4) < dg;  // wave-uniform
        uint4 nkv;
        int s_fut = s_nxt;
        if (more) {
          nkv = KV8[(size_t)s_nxt * 16 + kvo];
          s_fut = csr[st + min(i + 8 + e4, dgm1)];
        }
        // ---- compute on current ----
        float2v p2 = cvt2lo(ckv.x) * qv[0];
        p2 += cvt2hi(ckv.x) * qv[1];
        p2 += cvt2lo(ckv.y) * qv[2];
        p2 += cvt2hi(ckv.y) * qv[3];
        float p = p2.x + p2.y;
        p += __shfl_xor(p, 1);  // combine the two half-heads
        float sc = __expf(fminf(fmaxf(p * 0.25f, -5.f), 5.f));
        sc = ((i + e4) < dg) ? sc : 0.f;
        z += sc;
        float2v sv = {sc, sc};
        acc[0] += cvt2lo(ckv.z) * sv;
        acc[1] += cvt2hi(ckv.z) * sv;
        acc[2] += cvt2lo(ckv.w) * sv;
        acc[3] += cvt2hi(ckv.w) * sv;
        if (!more) break;
        ckv = nkv;
        s_nxt = s_fut;
        i += 4;
      }
    }
    // reduce across the 4 edge slots (lane bits 4,5)
#pragma unroll
    for (int m = 16; m <= 32; m <<= 1) {
      z += __shfl_xor(z, m);
#pragma unroll
      for (int d = 0; d < 4; ++d) {
        acc[d].x += __shfl_xor(acc[d].x, m);
        acc[d].y += __shfl_xor(acc[d].y, m);
      }
    }
    if (e4 == 0) {
      float inv = (z > 0.f) ? 1.f / z : 1.f;
      unsigned r[4];
#pragma unroll
      for (int j = 0; j < 4; ++j)
        r[j] = (unsigned)f2b_bits(acc[j].x * inv) |
               ((unsigned)f2b_bits(acc[j].y * inv) << 16);
      AT4[(size_t)node * 16 + kvo] = make_uint4(r[0], r[1], r[2], r[3]);
    }
  }
}

// ---------------- launch ----------------
extern "C" void kernel_launch(void* const* d_in, const int* in_sizes, int n_in,
                              void* d_out, int out_size, void* d_ws, size_t ws_size,
                              hipStream_t stream) {
  const float* h = (const float*)d_in[0];
  const int* src = (const int*)d_in[1];
  const int* dst = (const int*)d_in[2];
  const float* Wq = (const float*)d_in[3];
  const float* Wk = (const float*)d_in[4];
  const float* Wv = (const float*)d_in[5];
  const float* Wo = (const float*)d_in[6];
  const float* bo = (const float*)d_in[7];
  const float* g1 = (const float*)d_in[8];
  const float* b1 = (const float*)d_in[9];
  const float* g2 = (const float*)d_in[10];
  const float* b2 = (const float*)d_in[11];
  const float* W1 = (const float*)d_in[12];
  const float* c1 = (const float*)d_in[13];
  const float* W2 = (const float*)d_in[14];
  const float* c2 = (const float*)d_in[15];

  const int N = in_sizes[0] / D;
  const int E = in_sizes[1];
  const int B = (N + 255) >> 8;
  const int ntiles = N >> 4;

  char* p = (char*)d_ws;
  auto carve = [&](size_t bytes) {
    char* r = p;
    p += (bytes + 255) & ~(size_t)255;
    return r;
  };
  short* ATb = (short*)carve((size_t)N * D * 2);
  short* Qb = (short*)carve((size_t)N * D * 2);        // later hh
  unsigned char* KVb = (unsigned char*)carve((size_t)N * 256);  // fp8 K|V, 256 B/node
  short* wq = (short*)carve(16384 * 2);
  short* wk = (short*)carve(16384 * 2);
  short* wv = (short*)carve(16384 * 2);
  short* wo = (short*)carve(16384 * 2);
  short* w1 = (short*)carve(32768 * 2);
  short* w2 = (short*)carve(32768 * 2);
  int* deg = (int*)carve((size_t)N * 4);
  int* offs = (int*)carve((size_t)N * 4);
  int* bh = (int*)carve(MAXB * 4);
  int* bbase = (int*)carve(MAXB * 4);
  int* bcur = (int*)carve(MAXB * 4);
  unsigned* binned = (unsigned*)carve((size_t)E * 4);
  int* csr = (int*)carve((size_t)E * 4);
  short* hh = Qb;  // alias: Q dead after attn_agg

  hipMemsetAsync(bh, 0, MAXB * 4, stream);
  k_bhist_cast<<<1024, 256, 0, stream>>>(
      dst, bh, E, Wq, Wk, Wv, Wo, W1, W2,
      (__hip_bfloat16*)wq, (__hip_bfloat16*)wk, (__hip_bfloat16*)wv,
      (__hip_bfloat16*)wo, (__hip_bfloat16*)w1, (__hip_bfloat16*)w2);
  k_bscan<<<1, MAXB, 0, stream>>>(bh, bbase, bcur, B);
  k_bin<<<(E + 4095) / 4096, 256, 0, stream>>>(src, dst, bcur, binned, E);
  k_fine<<<B, 256, 0, stream>>>(binned, bh, bbase, deg, offs, csr, N);

  gemm_qkv7<<<256, 512, 0, stream>>>(h, (const uint4*)wq, (const uint4*)wk,
                                     (const uint4*)wv, (__hip_bfloat16*)Qb, KVb, N);

  attn_agg5<<<(N + 3) >> 2, 256, 0, stream>>>((const uint4*)Qb, (const uint4*)KVb,
                                              offs, deg, csr, (uint4*)ATb, N);

  ln_gemm2<<<(ntiles + 7) / 8, 512, 0, stream>>>(
      ATb, (const uint4*)wo, bo, h, g1, b1, (__hip_bfloat16*)hh, N);
  ffn_ln<<<256, 512, 0, stream>>>(hh, (const uint4*)w1, c1, (const uint4*)w2, c2,
                                  g2, b2, (float*)d_out, N);
}

// Round 11
// 356.060 us; speedup vs baseline: 1.4128x; 1.4128x over previous
//
#include <hip/hip_runtime.h>
#include <hip/hip_bf16.h>

#define D 128
#define MAXB 512

typedef __attribute__((ext_vector_type(8))) short short8;
typedef __attribute__((ext_vector_type(4))) float float4v;
typedef __attribute__((ext_vector_type(2))) float float2v;

__device__ __forceinline__ float4v mfma16(short8 a, short8 b, float4v c) {
  return __builtin_amdgcn_mfma_f32_16x16x32_bf16(a, b, c, 0, 0, 0);
}
__device__ __forceinline__ float b2f(__hip_bfloat16 x) { return __bfloat162float(x); }
__device__ __forceinline__ __hip_bfloat16 f2b(float x) { return __float2bfloat16(x); }
__device__ __forceinline__ unsigned short f2b_bits(float x) {
  __hip_bfloat16 h = __float2bfloat16(x);
  return *reinterpret_cast<unsigned short*>(&h);
}

__device__ __forceinline__ float ldf(const float* p, size_t i) { return p[i]; }
__device__ __forceinline__ float ldf(const __hip_bfloat16* p, size_t i) { return b2f(p[i]); }
__device__ __forceinline__ void stf(float* p, size_t i, float v) { p[i] = v; }
__device__ __forceinline__ void stf(__hip_bfloat16* p, size_t i, float v) { p[i] = f2b(v); }

// relaxed workgroup barrier: drain LDS ops only, leave global loads in flight.
__device__ __forceinline__ void bar_lds() {
  asm volatile("s_waitcnt lgkmcnt(0)\n\ts_barrier" ::: "memory");
}

// packed bf16-pair -> float2 (lo, hi)
__device__ __forceinline__ float2v up2(unsigned w) {
  float2v r;
  r.x = __uint_as_float(w << 16);
  r.y = __uint_as_float(w & 0xffff0000u);
  return r;
}
// fp8 e4m3 (OCP on gfx950) encode/decode via the HW cvt pair — self-consistent.
__device__ __forceinline__ unsigned char f2fp8(float x) {
  int r = __builtin_amdgcn_cvt_pk_fp8_f32(x, x, 0, false);
  return (unsigned char)(r & 0xff);
}
__device__ __forceinline__ float2v cvt2lo(unsigned w) {
  return __builtin_amdgcn_cvt_pk_f32_fp8(w, false);
}
__device__ __forceinline__ float2v cvt2hi(unsigned w) {
  return __builtin_amdgcn_cvt_pk_f32_fp8(w, true);
}

__device__ __forceinline__ short8 cvt8(float4 u0, float4 u1) {
  short8 a;
  a[0] = (short)f2b_bits(u0.x); a[1] = (short)f2b_bits(u0.y);
  a[2] = (short)f2b_bits(u0.z); a[3] = (short)f2b_bits(u0.w);
  a[4] = (short)f2b_bits(u1.x); a[5] = (short)f2b_bits(u1.y);
  a[6] = (short)f2b_bits(u1.z); a[7] = (short)f2b_bits(u1.w);
  return a;
}

// ------- bucket histogram (LDS-combined) + weight cast folded in (independent) ----
// frag layout for weights (KxNcol): out[((c*4+quad)*Ncol + col)*8 + j]
//   = W[(c*32 + quad*8 + j)*Ncol + col]  -> one aligned 16-B load per fragment.
__global__ __launch_bounds__(256) void k_bhist_cast(
    const int* __restrict__ dst, int* __restrict__ bh, int E,
    const float* __restrict__ wq, const float* __restrict__ wk,
    const float* __restrict__ wv, const float* __restrict__ wo,
    const float* __restrict__ w1, const float* __restrict__ w2,
    __hip_bfloat16* __restrict__ oq, __hip_bfloat16* __restrict__ ok,
    __hip_bfloat16* __restrict__ ov, __hip_bfloat16* __restrict__ oo,
    __hip_bfloat16* __restrict__ o1, __hip_bfloat16* __restrict__ o2) {
  __shared__ int cnt[MAXB];
  const int t = threadIdx.x;
  const int gid = blockIdx.x * 256 + t;
  for (int i = t; i < MAXB; i += 256) cnt[i] = 0;
  __syncthreads();
  for (int e = gid; e < E; e += gridDim.x * 256) atomicAdd(&cnt[dst[e] >> 8], 1);
  // weight cast: 131072 elements, done by the first 131072 threads
  int i = gid;
  if (i < 65536) {  // wq, wk, wv, wo : K=128, Ncol=128
    int m = i & 16383;
    int which = i >> 14;
    const float* s = (which == 0) ? wq : (which == 1) ? wk : (which == 2) ? wv : wo;
    __hip_bfloat16* o = (which == 0) ? oq : (which == 1) ? ok : (which == 2) ? ov : oo;
    int j = m & 7, t2 = m >> 3;
    int col = t2 & 127, cq = t2 >> 7;
    o[m] = f2b(s[((cq >> 2) * 32 + (cq & 3) * 8 + j) * 128 + col]);
  } else if (i < 98304) {  // w1 : K=128, Ncol=256
    int m = i - 65536;
    int j = m & 7, t2 = m >> 3;
    int col = t2 & 255, cq = t2 >> 8;
    o1[m] = f2b(w1[((cq >> 2) * 32 + (cq & 3) * 8 + j) * 256 + col]);
  } else if (i < 131072) {  // w2 : K=256, Ncol=128
    int m = i - 98304;
    int j = m & 7, t2 = m >> 3;
    int col = t2 & 127, cq = t2 >> 7;
    o2[m] = f2b(w2[((cq >> 2) * 32 + (cq & 3) * 8 + j) * 128 + col]);
  }
  __syncthreads();
  for (int k = t; k < MAXB; k += 256)
    if (cnt[k]) atomicAdd(&bh[k], cnt[k]);
}

__global__ void k_bscan(const int* __restrict__ bh, int* __restrict__ bbase,
                        int* __restrict__ bcur, int B) {
  __shared__ int sd[MAXB];
  int t = threadIdx.x;
  int v = (t < B) ? bh[t] : 0;
  sd[t] = v;
  __syncthreads();
  for (int o = 1; o < MAXB; o <<= 1) {
    int x = (t >= o) ? sd[t - o] : 0;
    __syncthreads();
    sd[t] += x;
    __syncthreads();
  }
  if (t < B) {
    int e = sd[t] - v;
    bbase[t] = e;
    bcur[t] = e;
  }
}

// each block bins 4096 edges into contiguous per-bucket runs (packed 32-bit)
__global__ __launch_bounds__(256) void k_bin(const int* __restrict__ src,
                                             const int* __restrict__ dst,
                                             int* __restrict__ bcur,
                                             unsigned* __restrict__ binned, int E) {
  __shared__ int cnt[MAXB];
  __shared__ int base[MAXB];
  const int t = threadIdx.x;
  const int e0 = blockIdx.x * 4096;
  for (int i = t; i < MAXB; i += 256) cnt[i] = 0;
  __syncthreads();
  int myb[16], myr[16];
  unsigned pk[16];
#pragma unroll
  for (int j = 0; j < 16; ++j) {
    int e = e0 + j * 256 + t;
    if (e < E) {
      int d = dst[e];
      pk[j] = ((unsigned)src[e] << 8) | (unsigned)(d & 255);
      int b = d >> 8;
      myb[j] = b;
      myr[j] = atomicAdd(&cnt[b], 1);
    } else {
      myb[j] = -1;
    }
  }
  __syncthreads();
  for (int i = t; i < MAXB; i += 256)
    base[i] = cnt[i] ? atomicAdd(&bcur[i], cnt[i]) : 0;
  __syncthreads();
#pragma unroll
  for (int j = 0; j < 16; ++j)
    if (myb[j] >= 0) binned[(size_t)base[myb[j]] + myr[j]] = pk[j];
}

// one block per bucket: per-node deg/offs + LDS-local fine scatter into csr
__global__ __launch_bounds__(256) void k_fine(const unsigned* __restrict__ binned,
                                              const int* __restrict__ bh,
                                              const int* __restrict__ bbase,
                                              int* __restrict__ deg,
                                              int* __restrict__ offs,
                                              int* __restrict__ csr, int N) {
  __shared__ int cnt[256];
  __shared__ int cur[256];
  __shared__ int sd[256];
  const int b = blockIdx.x, t = threadIdx.x;
  const int node0 = b << 8;
  cnt[t] = 0;
  __syncthreads();
  const int s0 = bbase[b], len = bh[b];
  for (int i = t; i < len; i += 256) atomicAdd(&cnt[binned[(size_t)s0 + i] & 255], 1);
  __syncthreads();
  int v = cnt[t];
  sd[t] = v;
  __syncthreads();
  for (int o = 1; o < 256; o <<= 1) {
    int x = (t >= o) ? sd[t - o] : 0;
    __syncthreads();
    sd[t] += x;
    __syncthreads();
  }
  int excl = sd[t] - v;
  cur[t] = excl;
  int node = node0 + t;
  if (node < N) {
    deg[node] = v;
    offs[node] = s0 + excl;
  }
  __syncthreads();
  for (int i = t; i < len; i += 256) {
    unsigned ed = binned[(size_t)s0 + i];
    int p = atomicAdd(&cur[ed & 255], 1);
    csr[s0 + p] = (int)(ed >> 8);
  }
}

// ------- fused QKV GEMM v8: wave-per-tile, SEQUENTIAL Q/K/V passes (low VGPR) ----
// One acc[8] reused across three passes (disjoint lifetimes) -> no spill.
__global__ __launch_bounds__(512, 2) void gemm_qkv8(const float* __restrict__ A,
                                                    const uint4* __restrict__ wqF,
                                                    const uint4* __restrict__ wkF,
                                                    const uint4* __restrict__ wvF,
                                                    __hip_bfloat16* __restrict__ Q,
                                                    unsigned char* __restrict__ KV8,
                                                    int Nrow) {
  __shared__ short W[3 * 16384];  // 96 KB: Wq | Wk | Wv, frag-ordered
  const int t = threadIdx.x;
  {
    uint4* W4 = (uint4*)W;
    for (int i = t; i < 2048; i += 512) {
      W4[i] = wqF[i];
      W4[i + 2048] = wkF[i];
      W4[i + 4096] = wvF[i];
    }
  }
  __syncthreads();
  const int w = t >> 6;            // wave 0..7 — independent tile stream
  const int lane = t & 63;
  const int n = lane & 15, quad = lane >> 4;
  const int ntiles = Nrow >> 4;
  const int step = gridDim.x * 8;
  int rt = blockIdx.x * 8 + w;
  if (rt >= ntiles) return;
  float4 u[8];
  {
    const float* Ap = A + (size_t)(rt * 16 + n) * 128 + quad * 8;
#pragma unroll
    for (int c = 0; c < 4; ++c) {
      u[2 * c] = *(const float4*)(Ap + c * 32);
      u[2 * c + 1] = *(const float4*)(Ap + c * 32 + 4);
    }
  }
  while (true) {
    const int rtn = rt + step;
    const bool more = rtn < ntiles;
    float4 un[8];
    if (more) {  // 1-deep prefetch
      const float* Ap = A + (size_t)(rtn * 16 + n) * 128 + quad * 8;
#pragma unroll
      for (int c = 0; c < 4; ++c) {
        un[2 * c] = *(const float4*)(Ap + c * 32);
        un[2 * c + 1] = *(const float4*)(Ap + c * 32 + 4);
      }
    }
    short8 a[4];
#pragma unroll
    for (int c = 0; c < 4; ++c) a[c] = cvt8(u[2 * c], u[2 * c + 1]);
    float4v acc[8];
    // ---- pass 1: Q ----
#pragma unroll
    for (int ct2 = 0; ct2 < 8; ++ct2) acc[ct2] = (float4v){0.f, 0.f, 0.f, 0.f};
#pragma unroll
    for (int c = 0; c < 4; ++c) {
      const int fb = ((c * 4 + quad) * 128 + n) * 8;
#pragma unroll
      for (int ct2 = 0; ct2 < 8; ++ct2)
        acc[ct2] = mfma16(a[c], *(const short8*)&W[fb + ct2 * 128], acc[ct2]);
    }
#pragma unroll
    for (int r = 0; r < 4; ++r) {
      const size_t qb = (size_t)(rt * 16 + quad * 4 + r) * 128 + n;
#pragma unroll
      for (int ct2 = 0; ct2 < 8; ++ct2) Q[qb + ct2 * 16] = f2b(acc[ct2][r]);
    }
    // ---- pass 2: K ----
#pragma unroll
    for (int ct2 = 0; ct2 < 8; ++ct2) acc[ct2] = (float4v){0.f, 0.f, 0.f, 0.f};
#pragma unroll
    for (int c = 0; c < 4; ++c) {
      const int fb = ((c * 4 + quad) * 128 + n) * 8;
#pragma unroll
      for (int ct2 = 0; ct2 < 8; ++ct2)
        acc[ct2] = mfma16(a[c], *(const short8*)&W[16384 + fb + ct2 * 128], acc[ct2]);
    }
#pragma unroll
    for (int r = 0; r < 4; ++r) {
      const size_t kb = (size_t)(rt * 16 + quad * 4 + r) * 256 + ((n >> 3) << 4) + (n & 7);
#pragma unroll
      for (int ct2 = 0; ct2 < 8; ++ct2) KV8[kb + ct2 * 32] = f2fp8(acc[ct2][r]);
    }
    // ---- pass 3: V ----
#pragma unroll
    for (int ct2 = 0; ct2 < 8; ++ct2) acc[ct2] = (float4v){0.f, 0.f, 0.f, 0.f};
#pragma unroll
    for (int c = 0; c < 4; ++c) {
      const int fb = ((c * 4 + quad) * 128 + n) * 8;
#pragma unroll
      for (int ct2 = 0; ct2 < 8; ++ct2)
        acc[ct2] = mfma16(a[c], *(const short8*)&W[32768 + fb + ct2 * 128], acc[ct2]);
    }
#pragma unroll
    for (int r = 0; r < 4; ++r) {
      const size_t kb = (size_t)(rt * 16 + quad * 4 + r) * 256 + ((n >> 3) << 4) + (n & 7);
#pragma unroll
      for (int ct2 = 0; ct2 < 8; ++ct2) KV8[kb + ct2 * 32 + 8] = f2fp8(acc[ct2][r]);
    }
    if (!more) break;
#pragma unroll
    for (int i = 0; i < 8; ++i) u[i] = un[i];
    rt = rtn;
  }
}

// ------ GEMM + bias + residual + LayerNorm v2: one WAVE per 16-row tile ----------
// 32 MFMA per wave-iter; LN fully in-wave (shfl over n-lanes); zero loop barriers.
__global__ __launch_bounds__(512) void ln_gemm2(const short* __restrict__ A,
                                                const uint4* __restrict__ BF4,
                                                const float* __restrict__ bias,
                                                const float* __restrict__ resid,
                                                const float* __restrict__ gam,
                                                const float* __restrict__ bet,
                                                __hip_bfloat16* __restrict__ Out,
                                                int Nrow) {
  __shared__ short W[16384];  // 32 KB, frag-ordered (K=128 x 128 cols)
  const int t = threadIdx.x;
  {
    uint4* W4 = (uint4*)W;
    for (int i = t; i < 2048; i += 512) W4[i] = BF4[i];
  }
  __syncthreads();
  const int w = t >> 6;
  const int lane = t & 63;
  const int n = lane & 15, quad = lane >> 4;
  float gv[8], bv[8], biasv[8];
#pragma unroll
  for (int ct2 = 0; ct2 < 8; ++ct2) {
    gv[ct2] = gam[ct2 * 16 + n];
    bv[ct2] = bet[ct2 * 16 + n];
    biasv[ct2] = bias[ct2 * 16 + n];
  }
  const int ntiles = Nrow >> 4;
  for (int rt = blockIdx.x * 8 + w; rt < ntiles; rt += gridDim.x * 8) {
    const short8* Ap = (const short8*)(A + (size_t)(rt * 16 + n) * 128 + quad * 8);
    short8 a[4];
#pragma unroll
    for (int c = 0; c < 4; ++c) a[c] = Ap[c * 4];
    float4v acc[8];
#pragma unroll
    for (int ct2 = 0; ct2 < 8; ++ct2) acc[ct2] = (float4v){0.f, 0.f, 0.f, 0.f};
#pragma unroll
    for (int c = 0; c < 4; ++c) {
      const short8 af = a[c];
      const int fb = ((c * 4 + quad) * 128 + n) * 8;
#pragma unroll
      for (int ct2 = 0; ct2 < 8; ++ct2)
        acc[ct2] = mfma16(af, *(const short8*)&W[fb + ct2 * 128], acc[ct2]);
    }
    // bias + residual
#pragma unroll
    for (int r = 0; r < 4; ++r) {
      const size_t base = (size_t)(rt * 16 + quad * 4 + r) * 128 + n;
#pragma unroll
      for (int ct2 = 0; ct2 < 8; ++ct2)
        acc[ct2][r] += biasv[ct2] + resid[base + ct2 * 16];
    }
    // in-wave LayerNorm: rows (quad*4+r) live on the 16 n-lanes of this quad group
    float s[4] = {0.f, 0.f, 0.f, 0.f}, s2[4] = {0.f, 0.f, 0.f, 0.f};
#pragma unroll
    for (int ct2 = 0; ct2 < 8; ++ct2)
#pragma unroll
      for (int r = 0; r < 4; ++r) {
        float x = acc[ct2][r];
        s[r] += x;
        s2[r] += x * x;
      }
#pragma unroll
    for (int r = 0; r < 4; ++r)
#pragma unroll
      for (int o = 1; o <= 8; o <<= 1) {
        s[r] += __shfl_xor(s[r], o);
        s2[r] += __shfl_xor(s2[r], o);
      }
#pragma unroll
    for (int r = 0; r < 4; ++r) {
      float mean = s[r] * 0.0078125f;
      float var = s2[r] * 0.0078125f - mean * mean;
      float rstd = rsqrtf(var + 1e-5f);
      const size_t base = (size_t)(rt * 16 + quad * 4 + r) * 128 + n;
#pragma unroll
      for (int ct2 = 0; ct2 < 8; ++ct2)
        Out[base + ct2 * 16] = f2b((acc[ct2][r] - mean) * rstd * gv[ct2] + bv[ct2]);
    }
  }
}

// ------ fused FFN: W1+W2 in LDS (128 KB), ping-pong mid, 2 barriers/iter ----------
__global__ __launch_bounds__(512) void ffn_ln(const short* __restrict__ hh,
                                              const uint4* __restrict__ W1F4,
                                              const float* __restrict__ c1,
                                              const uint4* __restrict__ W2F4,
                                              const float* __restrict__ c2,
                                              const float* __restrict__ gam,
                                              const float* __restrict__ bet,
                                              float* __restrict__ Out, int Nrow) {
  __shared__ short W1[32768];         // 64 KB frag-ordered
  __shared__ short W2[32768];         // 64 KB frag-ordered
  __shared__ short mid[2][16][264];   // ping-pong
  __shared__ float tile[16][132];
  const int t = threadIdx.x;
  {
    uint4* a4 = (uint4*)W1;
    uint4* b4 = (uint4*)W2;
    for (int i = t; i < 4096; i += 512) {
      a4[i] = W1F4[i];
      b4[i] = W2F4[i];
    }
  }
  __syncthreads();
  const int lane = t & 63;
  const int wv = t >> 6;
  const int n = lane & 15, quad = lane >> 4;
  float b1v0 = c1[(wv * 2) * 16 + n], b1v1 = c1[(wv * 2 + 1) * 16 + n];
  float b2v = c2[wv * 16 + n];
  const int row2 = t >> 5, sub = t & 31;
  float ga0 = gam[sub],      ga1 = gam[sub + 32];
  float ga2 = gam[sub + 64], ga3 = gam[sub + 96];
  float be0 = bet[sub],      be1 = bet[sub + 32];
  float be2 = bet[sub + 64], be3 = bet[sub + 96];
  const int ntiles = Nrow >> 4;
  const __hip_bfloat16* hb = (const __hip_bfloat16*)hh;
  const int f1b0 = quad * 256 + (wv * 2) * 16 + n;
  const int f1b1 = quad * 256 + (wv * 2 + 1) * 16 + n;
  const int f2b = quad * 128 + wv * 16 + n;
  int rt = blockIdx.x;
  if (rt >= ntiles) return;
  short8 a[4];
  __hip_bfloat16 rs[4];
  {
    const short8* Ap = (const short8*)(hh + (size_t)(rt * 16 + n) * 128 + quad * 8);
#pragma unroll
    for (int c = 0; c < 4; ++c) a[c] = Ap[c * 4];
#pragma unroll
    for (int r = 0; r < 4; ++r)
      rs[r] = hb[(size_t)(rt * 16 + quad * 4 + r) * 128 + wv * 16 + n];
  }
  int mp = 0;
  while (true) {
    const int rtn = rt + gridDim.x;
    const bool more = rtn < ntiles;
    short8 an[4];
    __hip_bfloat16 rsn[4];
    if (more) {  // prefetch survives the relaxed barriers (lgkm-only drain)
      const short8* Ap = (const short8*)(hh + (size_t)(rtn * 16 + n) * 128 + quad * 8);
#pragma unroll
      for (int c = 0; c < 4; ++c) an[c] = Ap[c * 4];
#pragma unroll
      for (int r = 0; r < 4; ++r)
        rsn[r] = hb[(size_t)(rtn * 16 + quad * 4 + r) * 128 + wv * 16 + n];
    }
    // GEMM1: mid = relu(hh @ W1 + c1)
    float4v a10 = {0.f, 0.f, 0.f, 0.f}, a11 = a10;
#pragma unroll
    for (int c = 0; c < 4; ++c) {
      short8 f1a = *(const short8*)&W1[(f1b0 + c * 1024) * 8];
      short8 f1c = *(const short8*)&W1[(f1b1 + c * 1024) * 8];
      a10 = mfma16(a[c], f1a, a10);
      a11 = mfma16(a[c], f1c, a11);
    }
#pragma unroll
    for (int r = 0; r < 4; ++r) {
      mid[mp][quad * 4 + r][(wv * 2) * 16 + n] = (short)f2b_bits(fmaxf(a10[r] + b1v0, 0.f));
      mid[mp][quad * 4 + r][(wv * 2 + 1) * 16 + n] = (short)f2b_bits(fmaxf(a11[r] + b1v1, 0.f));
    }
    bar_lds();
    // GEMM2: acc = mid @ W2 over K=256
    float4v acc = {0.f, 0.f, 0.f, 0.f};
#pragma unroll
    for (int c = 0; c < 8; ++c) {
      short8 am = *(const short8*)&mid[mp][n][quad * 8 + c * 32];
      short8 f2 = *(const short8*)&W2[(f2b + c * 512) * 8];
      acc = mfma16(am, f2, acc);
    }
#pragma unroll
    for (int r = 0; r < 4; ++r)
      tile[quad * 4 + r][wv * 16 + n] = acc[r] + b2v + b2f(rs[r]);
    bar_lds();
    float x0 = tile[row2][sub], x1 = tile[row2][sub + 32];
    float x2 = tile[row2][sub + 64], x3 = tile[row2][sub + 96];
    float s = x0 + x1 + x2 + x3;
    float s2 = x0 * x0 + x1 * x1 + x2 * x2 + x3 * x3;
#pragma unroll
    for (int o = 16; o >= 1; o >>= 1) {
      s += __shfl_xor(s, o);
      s2 += __shfl_xor(s2, o);
    }
    float mean = s * 0.0078125f;
    float var = s2 * 0.0078125f - mean * mean;
    float rstd = rsqrtf(var + 1e-5f);
    size_t base = (size_t)(rt * 16 + row2) * 128;
    Out[base + sub]      = (x0 - mean) * rstd * ga0 + be0;
    Out[base + sub + 32] = (x1 - mean) * rstd * ga1 + be1;
    Out[base + sub + 64] = (x2 - mean) * rstd * ga2 + be2;
    Out[base + sub + 96] = (x3 - mean) * rstd * ga3 + be3;
    if (!more) break;
#pragma unroll
    for (int c = 0; c < 4; ++c) a[c] = an[c];
#pragma unroll
    for (int r = 0; r < 4; ++r) rs[r] = rsn[r];
    rt = rtn;
    mp ^= 1;
  }
}

// ---- attention aggregation v5: fp8 KV gather (256 B/edge), lane = (e4, hd, hf) ----
__global__ __launch_bounds__(256) void attn_agg5(const uint4* __restrict__ Q4,
                                                 const uint4* __restrict__ KV8,
                                                 const int* __restrict__ offs,
                                                 const int* __restrict__ deg,
                                                 const int* __restrict__ csr,
                                                 uint4* __restrict__ AT4, int N) {
  const int lane = threadIdx.x & 63;
  const int wv = threadIdx.x >> 6;
  const int e4 = lane >> 4;        // 0..3  edge slot
  const int hd = (lane >> 1) & 7;  // head
  const int hf = lane & 1;         // half-head: dims hf*8 .. hf*8+7
  const int kvo = hd * 2 + hf;     // uint4 index within a node's 16 x 16B
  for (int node = blockIdx.x * 4 + wv; node < N; node += gridDim.x * 4) {
    uint4 qa = Q4[(size_t)node * 16 + kvo];
    float2v qv[4];
    qv[0] = up2(qa.x); qv[1] = up2(qa.y); qv[2] = up2(qa.z); qv[3] = up2(qa.w);
    float2v acc[4];
#pragma unroll
    for (int d = 0; d < 4; ++d) acc[d] = (float2v){0.f, 0.f};
    float z = 0.f;
    const int st = offs[node], dg = deg[node];
    if (dg > 0) {
      const int dgm1 = dg - 1;
      int s_cur = csr[st + min(e4, dgm1)];
      int s_nxt = (dg > 4) ? csr[st + min(4 + e4, dgm1)] : s_cur;
      uint4 ckv = KV8[(size_t)s_cur * 16 + kvo];
      int i = 0;
      while (true) {
        const bool more = (i + 4) < dg;  // wave-uniform
        uint4 nkv;
        int s_fut = s_nxt;
        if (more) {
          nkv = KV8[(size_t)s_nxt * 16 + kvo];
          s_fut = csr[st + min(i + 8 + e4, dgm1)];
        }
        // ---- compute on current ----
        float2v p2 = cvt2lo(ckv.x) * qv[0];
        p2 += cvt2hi(ckv.x) * qv[1];
        p2 += cvt2lo(ckv.y) * qv[2];
        p2 += cvt2hi(ckv.y) * qv[3];
        float p = p2.x + p2.y;
        p += __shfl_xor(p, 1);  // combine the two half-heads
        float sc = __expf(fminf(fmaxf(p * 0.25f, -5.f), 5.f));
        sc = ((i + e4) < dg) ? sc : 0.f;
        z += sc;
        float2v sv = {sc, sc};
        acc[0] += cvt2lo(ckv.z) * sv;
        acc[1] += cvt2hi(ckv.z) * sv;
        acc[2] += cvt2lo(ckv.w) * sv;
        acc[3] += cvt2hi(ckv.w) * sv;
        if (!more) break;
        ckv = nkv;
        s_nxt = s_fut;
        i += 4;
      }
    }
    // reduce across the 4 edge slots (lane bits 4,5)
#pragma unroll
    for (int m = 16; m <= 32; m <<= 1) {
      z += __shfl_xor(z, m);
#pragma unroll
      for (int d = 0; d < 4; ++d) {
        acc[d].x += __shfl_xor(acc[d].x, m);
        acc[d].y += __shfl_xor(acc[d].y, m);
      }
    }
    if (e4 == 0) {
      float inv = (z > 0.f) ? 1.f / z : 1.f;
      unsigned r[4];
#pragma unroll
      for (int j = 0; j < 4; ++j)
        r[j] = (unsigned)f2b_bits(acc[j].x * inv) |
               ((unsigned)f2b_bits(acc[j].y * inv) << 16);
      AT4[(size_t)node * 16 + kvo] = make_uint4(r[0], r[1], r[2], r[3]);
    }
  }
}

// ---------------- launch ----------------
extern "C" void kernel_launch(void* const* d_in, const int* in_sizes, int n_in,
                              void* d_out, int out_size, void* d_ws, size_t ws_size,
                              hipStream_t stream) {
  const float* h = (const float*)d_in[0];
  const int* src = (const int*)d_in[1];
  const int* dst = (const int*)d_in[2];
  const float* Wq = (const float*)d_in[3];
  const float* Wk = (const float*)d_in[4];
  const float* Wv = (const float*)d_in[5];
  const float* Wo = (const float*)d_in[6];
  const float* bo = (const float*)d_in[7];
  const float* g1 = (const float*)d_in[8];
  const float* b1 = (const float*)d_in[9];
  const float* g2 = (const float*)d_in[10];
  const float* b2 = (const float*)d_in[11];
  const float* W1 = (const float*)d_in[12];
  const float* c1 = (const float*)d_in[13];
  const float* W2 = (const float*)d_in[14];
  const float* c2 = (const float*)d_in[15];

  const int N = in_sizes[0] / D;
  const int E = in_sizes[1];
  const int B = (N + 255) >> 8;
  const int ntiles = N >> 4;

  char* p = (char*)d_ws;
  auto carve = [&](size_t bytes) {
    char* r = p;
    p += (bytes + 255) & ~(size_t)255;
    return r;
  };
  short* ATb = (short*)carve((size_t)N * D * 2);
  short* Qb = (short*)carve((size_t)N * D * 2);        // later hh
  unsigned char* KVb = (unsigned char*)carve((size_t)N * 256);  // fp8 K|V, 256 B/node
  short* wq = (short*)carve(16384 * 2);
  short* wk = (short*)carve(16384 * 2);
  short* wv = (short*)carve(16384 * 2);
  short* wo = (short*)carve(16384 * 2);
  short* w1 = (short*)carve(32768 * 2);
  short* w2 = (short*)carve(32768 * 2);
  int* deg = (int*)carve((size_t)N * 4);
  int* offs = (int*)carve((size_t)N * 4);
  int* bh = (int*)carve(MAXB * 4);
  int* bbase = (int*)carve(MAXB * 4);
  int* bcur = (int*)carve(MAXB * 4);
  unsigned* binned = (unsigned*)carve((size_t)E * 4);
  int* csr = (int*)carve((size_t)E * 4);
  short* hh = Qb;  // alias: Q dead after attn_agg

  hipMemsetAsync(bh, 0, MAXB * 4, stream);
  k_bhist_cast<<<1024, 256, 0, stream>>>(
      dst, bh, E, Wq, Wk, Wv, Wo, W1, W2,
      (__hip_bfloat16*)wq, (__hip_bfloat16*)wk, (__hip_bfloat16*)wv,
      (__hip_bfloat16*)wo, (__hip_bfloat16*)w1, (__hip_bfloat16*)w2);
  k_bscan<<<1, MAXB, 0, stream>>>(bh, bbase, bcur, B);
  k_bin<<<(E + 4095) / 4096, 256, 0, stream>>>(src, dst, bcur, binned, E);
  k_fine<<<B, 256, 0, stream>>>(binned, bh, bbase, deg, offs, csr, N);

  gemm_qkv8<<<256, 512, 0, stream>>>(h, (const uint4*)wq, (const uint4*)wk,
                                     (const uint4*)wv, (__hip_bfloat16*)Qb, KVb, N);

  attn_agg5<<<(N + 3) >> 2, 256, 0, stream>>>((const uint4*)Qb, (const uint4*)KVb,
                                              offs, deg, csr, (uint4*)ATb, N);

  ln_gemm2<<<(ntiles + 7) / 8, 512, 0, stream>>>(
      ATb, (const uint4*)wo, bo, h, g1, b1, (__hip_bfloat16*)hh, N);
  ffn_ln<<<256, 512, 0, stream>>>(hh, (const uint4*)w1, c1, (const uint4*)w2, c2,
                                  g2, b2, (float*)d_out, N);
}